// Round 7
// baseline (117.419 us; speedup 1.0000x reference)
//
#include <hip/hip_runtime.h>

// out[b,o,h,w] = sum_{c,k} (coef[k]/12.5) * rint( sum_j (12.5*w[k,c,o,j])*x_j + 12.5*b[k,c,o] )
// R7: R5's packed-fp32 wave shape (1 o, 2 rows, lane=w, 32 waves/CU) + double-buffered
// LDS x-staging (zero-padded cols -> no boundary cndmask; ds_read2-style tap pairs)
// + XCD-keyed grid (id%8 = hblk) so same-slab blocks share one XCD's L2.

typedef float v2f __attribute__((ext_vector_type(2)));

#define NB     8
#define NC     32
#define NO     32
#define NH     64
#define NW     64
#define NBATCH 8
#define FST    10                  // 9 taps + bias
#define PLANE  (NH * NW)
#define WCSTEP (NO * NB * FST)     // dwords per c step in wq
#define LROW   66                  // LDS row stride (64 + 2 zero border cols)
#define NROWS  10                  // staged rows per block (8 outputs + halo)

// wq layout: [c:32][o:32][k:8][10]; value = 12.5*w, [9] = 12.5*bias
__global__ void prep_wq(const float* __restrict__ w, const float* __restrict__ bias,
                        float* __restrict__ wq) {
    int idx = blockIdx.x * 256 + threadIdx.x;      // (c*32+o)*8+k
    if (idx >= NC * NO * NB) return;
    int k  = idx & 7;
    int ch = idx >> 3;                             // c*32+o
    const float* ws = w + ((size_t)k * (NC * NO) + ch) * 9;
    float* dst = wq + (size_t)idx * FST;
#pragma unroll
    for (int j = 0; j < 9; ++j) dst[j] = 12.5f * ws[j];
    dst[9] = 12.5f * bias[k * (NC * NO) + ch];
}

// Block = 4 waves = 8 output rows, one o. Grid (8 hb, 32 o, 8 b) -> id%8 = hb (XCD key).
__global__ __launch_bounds__(256, 8) void demolition_conv(
        const float* __restrict__ x, const float* __restrict__ wq,
        float* __restrict__ out) {
    __shared__ float xs[2][NROWS * LROW];

    const int tid  = threadIdx.x;
    const int w    = tid & 63;
    const int wave = tid >> 6;
    const int hb   = blockIdx.x;                   // 0..7  (XCD key)
    const int o    = blockIdx.y;                   // 0..31
    const int b    = blockIdx.z;
    const int hbase = hb * 8;

    // zero the padded border columns (cols 0 and 65, rows 0..9, both buffers)
    if (tid < 2 * NROWS * 2) {                     // 40 threads
        int bu = tid >= 2 * NROWS;
        int r  = (tid % (2 * NROWS)) >> 1;
        int cc = (tid & 1) ? (LROW - 1) : 0;
        xs[bu][r * LROW + cc] = 0.f;
    }

    const float ckq[8] = {
        -128.f / 127.f / 12.5f,  1.f / 127.f / 12.5f,  2.f / 127.f / 12.5f,
           4.f / 127.f / 12.5f,  8.f / 127.f / 12.5f, 16.f / 127.f / 12.5f,
          32.f / 127.f / 12.5f, 64.f / 127.f / 12.5f };

    // staging slots: 640 entries (10 rows x 64 cols) over 256 threads, 3 passes
    const int i0 = tid, i1 = tid + 256, i2 = tid + 512;
    const int r0s = i0 >> 6, c0s = i0 & 63;
    const int r1s = i1 >> 6, c1s = i1 & 63;
    const int r2s = i2 >> 6, c2s = i2 & 63;
    const bool a2 = (i2 < NROWS * 64);
    const int g0 = hbase - 1 + r0s;                // global input rows (may be OOB)
    const int g1 = hbase - 1 + r1s;
    const int g2 = hbase - 1 + r2s;
    const bool v0 = (unsigned)g0 < NH;
    const bool v1 = (unsigned)g1 < NH;
    const bool v2 = a2 && ((unsigned)g2 < NH);

    const float* xb = x + ((size_t)b * NC) * PLANE;    // c=0 plane for this batch

    // stage c=0 into buffer 0
    {
        float s0 = v0 ? xb[g0 * NW + c0s] : 0.f;
        float s1 = v1 ? xb[g1 * NW + c1s] : 0.f;
        float s2 = v2 ? xb[g2 * NW + c2s] : 0.f;
        xs[0][r0s * LROW + c0s + 1] = s0;
        xs[0][r1s * LROW + c1s + 1] = s1;
        if (a2) xs[0][r2s * LROW + c2s + 1] = s2;
    }
    __syncthreads();

    v2f acc = {0.f, 0.f};
    int woff = o * (NB * FST);

#pragma unroll 1
    for (int c = 0; c < NC; ++c, woff += WCSTEP) {
        // prefetch c+1's rows (loads issued BEFORE compute, written to LDS after)
        float s0 = 0.f, s1 = 0.f, s2 = 0.f;
        if (c + 1 < NC) {
            const float* xp = xb + (size_t)(c + 1) * PLANE;
            s0 = v0 ? xp[g0 * NW + c0s] : 0.f;
            s1 = v1 ? xp[g1 * NW + c1s] : 0.f;
            s2 = v2 ? xp[g2 * NW + c2s] : 0.f;
        }

        // tap pairs from staged buffer: t[3r+cc] = { row(2*wave+r), row(2*wave+r+1) } at col w+cc
        const float* xw = &xs[c & 1][(wave * 2) * LROW + w];
        v2f t[9];
#pragma unroll
        for (int r = 0; r < 3; ++r)
#pragma unroll
            for (int cc = 0; cc < 3; ++cc) {
                t[3 * r + cc].x = xw[r * LROW + cc];
                t[3 * r + cc].y = xw[(r + 1) * LROW + cc];
            }

        const float* wp = wq + __builtin_amdgcn_readfirstlane(woff);
#pragma unroll
        for (int k = 0; k < NB; ++k) {
            const float* f = wp + k * FST;         // compile-time imm offsets off scalar base
            v2f s; s.x = f[9]; s.y = f[9];         // pre-scaled bias (both rows)
#pragma unroll
            for (int j = 0; j < 9; ++j) {
                v2f wv; wv.x = f[j]; wv.y = f[j];  // uniform splat
                s = __builtin_elementwise_fma(wv, t[j], s);
            }
            v2f rr; rr.x = rintf(s.x); rr.y = rintf(s.y);
            v2f cv; cv.x = ckq[k]; cv.y = ckq[k];
            acc = __builtin_elementwise_fma(cv, rr, acc);
        }

        if (c + 1 < NC) {
            float* d = xs[(c + 1) & 1];
            d[r0s * LROW + c0s + 1] = s0;
            d[r1s * LROW + c1s + 1] = s1;
            if (a2) d[r2s * LROW + c2s + 1] = s2;
        }
        __syncthreads();
    }

    const int h0 = hbase + wave * 2;
    float* op = out + (((size_t)b * NO + o) * NH + h0) * NW + w;
    op[0]  = acc.x;
    op[NW] = acc.y;
}

extern "C" void kernel_launch(void* const* d_in, const int* in_sizes, int n_in,
                              void* d_out, int out_size, void* d_ws, size_t ws_size,
                              hipStream_t stream) {
    const float* x    = (const float*)d_in[0];   // [8,32,64,64]
    const float* wt   = (const float*)d_in[1];   // [8,1024,1,3,3]
    const float* bias = (const float*)d_in[2];   // [8,1024]
    float* out = (float*)d_out;                  // [8,32,64,64]
    float* wq  = (float*)d_ws;                   // 8192*10 floats = 320 KiB

    prep_wq<<<(NC * NO * NB + 255) / 256, 256, 0, stream>>>(wt, bias, wq);

    dim3 grid(8, NO, NBATCH);                    // (hb, o, b): dispatch id % 8 == hb
    demolition_conv<<<grid, 256, 0, stream>>>(x, wq, out);
}

// Round 8
// 73.554 us; speedup vs baseline: 1.5964x; 1.5964x over previous
//
#include <hip/hip_runtime.h>

// out[b,o,h,w] = sum_{c,k} (coef[k]/12.5) * rint( sum_j (12.5*w[k,c,o,j])*x_j + 12.5*b[k,c,o] )
// R8 = R5 (best, 79.3us: packed-fp32, 1 o + 2 rows per wave, 32 waves/CU, scalar-path weights)
//  + DPP wave_shr/shl neighbor exchange: 12 -> 4 global loads per c, zero-pad at w edges free
//  + XCD-keyed grid (blockIdx.x = h-slab) so each XCD's L2 owns one x slab (R7-proven FETCH cut).

typedef float v2f __attribute__((ext_vector_type(2)));

#define NB     8
#define NC     32
#define NO     32
#define NH     64
#define NW     64
#define NBATCH 8
#define FST    10                  // 9 taps + bias
#define PLANE  (NH * NW)
#define WCSTEP (NO * NB * FST)     // dwords per c step in wq

// wq layout: [c:32][o:32][k:8][10]; value = 12.5*w, [9] = 12.5*bias
__global__ void prep_wq(const float* __restrict__ w, const float* __restrict__ bias,
                        float* __restrict__ wq) {
    int idx = blockIdx.x * 256 + threadIdx.x;      // (c*32+o)*8+k
    if (idx >= NC * NO * NB) return;
    int k  = idx & 7;
    int ch = idx >> 3;                             // c*32+o
    const float* ws = w + ((size_t)k * (NC * NO) + ch) * 9;
    float* dst = wq + (size_t)idx * FST;
#pragma unroll
    for (int j = 0; j < 9; ++j) dst[j] = 12.5f * ws[j];
    dst[9] = 12.5f * bias[k * (NC * NO) + ch];
}

// lane w receives lane w-1's value; lane 0 -> 0 (bound_ctrl). (wave_shr:1 = 0x138)
__device__ __forceinline__ float dpp_left(float v) {
    return __builtin_bit_cast(float, __builtin_amdgcn_update_dpp(
        0, __builtin_bit_cast(int, v), 0x138, 0xf, 0xf, true));
}
// lane w receives lane w+1's value; lane 63 -> 0. (wave_shl:1 = 0x130)
__device__ __forceinline__ float dpp_right(float v) {
    return __builtin_bit_cast(float, __builtin_amdgcn_update_dpp(
        0, __builtin_bit_cast(int, v), 0x130, 0xf, 0xf, true));
}

// Wave = (b, o, row-pair h0,h0+1). lane = w (full row). Block = 4 waves, same o, 8 rows.
// Grid (8 hb, 32 o, 8 b): dispatch id % 8 == hb -> one x slab per XCD L2.
__global__ __launch_bounds__(256, 8) void demolition_conv(
        const float* __restrict__ x, const float* __restrict__ wq,
        float* __restrict__ out) {
    const int w    = threadIdx.x & 63;
    const int wave = threadIdx.x >> 6;
    const int hb   = blockIdx.x;                   // 0..7 (XCD key)
    const int o    = blockIdx.y;                   // 0..31
    const int b    = blockIdx.z;
    const int h0   = hb * 8 + wave * 2;            // 0..62 even

    const float ckq[8] = {
        -128.f / 127.f / 12.5f,  1.f / 127.f / 12.5f,  2.f / 127.f / 12.5f,
           4.f / 127.f / 12.5f,  8.f / 127.f / 12.5f, 16.f / 127.f / 12.5f,
          32.f / 127.f / 12.5f, 64.f / 127.f / 12.5f };

    v2f acc = {0.f, 0.f};                          // rows (h0, h0+1) for channel o

    const bool top = (h0 > 0), bot = (h0 < NH - 2);   // wave-uniform
    const int  rT  = top ? -NW : 0;        // clamped address for row h0-1
    const int  rB  = bot ? 2 * NW : NW;    // clamped address for row h0+2

    const float* xc = x + ((size_t)b * NC * NH + h0) * NW + w;
    int woff = o * (NB * FST);

    for (int c = 0; c < NC; ++c, xc += PLANE, woff += WCSTEP) {
        // 4 center-column loads (rows h0-1 .. h0+2); h-edge rows zeroed (wave-uniform)
        float xm1 = xc[rT];  if (!top) xm1 = 0.f;
        float x0  = xc[0];
        float x1  = xc[NW];
        float x2  = xc[rB];  if (!bot) x2 = 0.f;

        // neighbor columns via DPP (w-edges auto-zero via bound_ctrl)
        float lm1 = dpp_left(xm1), l0 = dpp_left(x0), l1 = dpp_left(x1), l2 = dpp_left(x2);
        float rm1 = dpp_right(xm1), r0 = dpp_right(x0), r1 = dpp_right(x1), r2 = dpp_right(x2);

        // packed taps: t[3r+cc] = { row h0-1+r, row h0+r } at col w+cc-1
        v2f t[9];
        t[0].x = lm1; t[0].y = l0;
        t[1].x = xm1; t[1].y = x0;
        t[2].x = rm1; t[2].y = r0;
        t[3].x = l0;  t[3].y = l1;
        t[4].x = x0;  t[4].y = x1;
        t[5].x = r0;  t[5].y = r1;
        t[6].x = l1;  t[6].y = l2;
        t[7].x = x1;  t[7].y = x2;
        t[8].x = r1;  t[8].y = r2;

        const float* wp = wq + __builtin_amdgcn_readfirstlane(woff);
#pragma unroll
        for (int k = 0; k < NB; ++k) {
            const float* f = wp + k * FST;         // compile-time imm offsets off scalar base
            v2f s; s.x = f[9]; s.y = f[9];         // pre-scaled bias (both rows)
#pragma unroll
            for (int j = 0; j < 9; ++j) {
                v2f wv; wv.x = f[j]; wv.y = f[j];  // uniform splat
                s = __builtin_elementwise_fma(wv, t[j], s);
            }
            v2f rr; rr.x = rintf(s.x); rr.y = rintf(s.y);
            v2f cv; cv.x = ckq[k]; cv.y = ckq[k];
            acc = __builtin_elementwise_fma(cv, rr, acc);
        }
    }

    float* op = out + (((size_t)b * NO + o) * NH + h0) * NW + w;
    op[0]  = acc.x;
    op[NW] = acc.y;
}

extern "C" void kernel_launch(void* const* d_in, const int* in_sizes, int n_in,
                              void* d_out, int out_size, void* d_ws, size_t ws_size,
                              hipStream_t stream) {
    const float* x    = (const float*)d_in[0];   // [8,32,64,64]
    const float* wt   = (const float*)d_in[1];   // [8,1024,1,3,3]
    const float* bias = (const float*)d_in[2];   // [8,1024]
    float* out = (float*)d_out;                  // [8,32,64,64]
    float* wq  = (float*)d_ws;                   // 8192*10 floats = 320 KiB

    prep_wq<<<(NC * NO * NB + 255) / 256, 256, 0, stream>>>(wt, bias, wq);

    dim3 grid(8, NO, NBATCH);                    // (hb, o, b): id % 8 == hb (XCD key)
    demolition_conv<<<grid, 256, 0, stream>>>(x, wq, out);
}

// Round 9
// 73.509 us; speedup vs baseline: 1.5973x; 1.0006x over previous
//
#include <hip/hip_runtime.h>

// out[b,o,h,w] = sum_{c,k} (coef[k]/12.5) * rint( sum_j (12.5*w[k,c,o,j])*x_j + 12.5*b[k,c,o] )
// R9 = R8 (73.5us: packed-fp32, 1 o + 2 rows/wave, DPP neighbor exchange, XCD-keyed grid)
//  + 1-deep x-load ping-pong prefetch (loads for c+1 issued before compute of c; zero extra VALU)
//  + weight layout [o][c][k][10]: per-block weight stream contiguous (10 KB) for K$/s_load batching.

typedef float v2f __attribute__((ext_vector_type(2)));

#define NB     8
#define NC     32
#define NO     32
#define NH     64
#define NW     64
#define NBATCH 8
#define FST    10                  // 9 taps + bias
#define PLANE  (NH * NW)
#define WCSTEP (NB * FST)          // dwords per c step in wq (contiguous per-o stream)

// wq layout: [o:32][c:32][k:8][10]; value = 12.5*w, [9] = 12.5*bias
__global__ void prep_wq(const float* __restrict__ w, const float* __restrict__ bias,
                        float* __restrict__ wq) {
    int idx = blockIdx.x * 256 + threadIdx.x;      // (o*32+c)*8+k
    if (idx >= NC * NO * NB) return;
    int k = idx & 7;
    int c = (idx >> 3) & 31;
    int o = idx >> 8;
    int ch = c * NO + o;                           // channel in original [k][1024] layout
    const float* ws = w + ((size_t)k * (NC * NO) + ch) * 9;
    float* dst = wq + (size_t)idx * FST;
#pragma unroll
    for (int j = 0; j < 9; ++j) dst[j] = 12.5f * ws[j];
    dst[9] = 12.5f * bias[k * (NC * NO) + ch];
}

// lane w receives lane w-1's value; lane 0 -> 0 (bound_ctrl). (wave_shr:1 = 0x138)
__device__ __forceinline__ float dpp_left(float v) {
    return __builtin_bit_cast(float, __builtin_amdgcn_update_dpp(
        0, __builtin_bit_cast(int, v), 0x138, 0xf, 0xf, true));
}
// lane w receives lane w+1's value; lane 63 -> 0. (wave_shl:1 = 0x130)
__device__ __forceinline__ float dpp_right(float v) {
    return __builtin_bit_cast(float, __builtin_amdgcn_update_dpp(
        0, __builtin_bit_cast(int, v), 0x130, 0xf, 0xf, true));
}

// One channel-step: DPP neighbor exchange + pack + 8 filters. FMA order == R8 (absmax canary).
__device__ __forceinline__ v2f step(float xm1, float x0, float x1, float x2,
                                    bool top, bool bot,
                                    const float* __restrict__ wp, v2f acc,
                                    const float* __restrict__ ckq) {
    if (!top) xm1 = 0.f;                           // wave-uniform
    if (!bot) x2  = 0.f;

    float lm1 = dpp_left(xm1), l0 = dpp_left(x0), l1 = dpp_left(x1), l2 = dpp_left(x2);
    float rm1 = dpp_right(xm1), r0 = dpp_right(x0), r1 = dpp_right(x1), r2 = dpp_right(x2);

    v2f t[9];
    t[0].x = lm1; t[0].y = l0;
    t[1].x = xm1; t[1].y = x0;
    t[2].x = rm1; t[2].y = r0;
    t[3].x = l0;  t[3].y = l1;
    t[4].x = x0;  t[4].y = x1;
    t[5].x = r0;  t[5].y = r1;
    t[6].x = l1;  t[6].y = l2;
    t[7].x = x1;  t[7].y = x2;
    t[8].x = r1;  t[8].y = r2;

#pragma unroll
    for (int k = 0; k < NB; ++k) {
        const float* f = wp + k * FST;             // compile-time imm offsets off scalar base
        v2f s; s.x = f[9]; s.y = f[9];             // pre-scaled bias (both rows)
#pragma unroll
        for (int j = 0; j < 9; ++j) {
            v2f wv; wv.x = f[j]; wv.y = f[j];      // uniform splat
            s = __builtin_elementwise_fma(wv, t[j], s);
        }
        v2f rr; rr.x = rintf(s.x); rr.y = rintf(s.y);
        v2f cv; cv.x = ckq[k]; cv.y = ckq[k];
        acc = __builtin_elementwise_fma(cv, rr, acc);
    }
    return acc;
}

// Wave = (b, o, row-pair h0,h0+1). lane = w. Block = 4 waves, same o, 8 rows.
// Grid (8 hb, 32 o, 8 b): dispatch id % 8 == hb -> one x slab per XCD L2.
__global__ __launch_bounds__(256, 8) void demolition_conv(
        const float* __restrict__ x, const float* __restrict__ wq,
        float* __restrict__ out) {
    const int w    = threadIdx.x & 63;
    const int wave = threadIdx.x >> 6;
    const int hb   = blockIdx.x;                   // 0..7 (XCD key)
    const int o    = blockIdx.y;                   // 0..31
    const int b    = blockIdx.z;
    const int h0   = hb * 8 + wave * 2;            // 0..62 even

    const float ckq[8] = {
        -128.f / 127.f / 12.5f,  1.f / 127.f / 12.5f,  2.f / 127.f / 12.5f,
           4.f / 127.f / 12.5f,  8.f / 127.f / 12.5f, 16.f / 127.f / 12.5f,
          32.f / 127.f / 12.5f, 64.f / 127.f / 12.5f };

    v2f acc = {0.f, 0.f};

    const bool top = (h0 > 0), bot = (h0 < NH - 2);
    const int  rT  = top ? -NW : 0;        // clamped address for row h0-1
    const int  rB  = bot ? 2 * NW : NW;    // clamped address for row h0+2

    const float* xc = x + ((size_t)b * NC * NH + h0) * NW + w;
    const float* wp = wq + __builtin_amdgcn_readfirstlane(o * (NC * NB * FST));

    // prologue: raw loads for c=0 (ping)
    float am1 = xc[rT], a0 = xc[0], a1 = xc[NW], a2 = xc[rB];

#pragma unroll 1
    for (int c = 0; c < NC; c += 2) {
        // prefetch c+1 (pong) — issued BEFORE compute of c
        const float* xn = xc + PLANE;
        float bm1 = xn[rT], b0 = xn[0], b1 = xn[NW], b2 = xn[rB];
        acc = step(am1, a0, a1, a2, top, bot, wp, acc, ckq);
        wp += WCSTEP;

        // prefetch c+2 (ping); clamp at tail (wave-uniform, loads harmless & unused)
        const float* xm = (c + 2 < NC) ? xn + PLANE : xn;
        am1 = xm[rT]; a0 = xm[0]; a1 = xm[NW]; a2 = xm[rB];
        acc = step(bm1, b0, b1, b2, top, bot, wp, acc, ckq);
        wp += WCSTEP;

        xc = xm;
    }

    float* op = out + (((size_t)b * NO + o) * NH + h0) * NW + w;
    op[0]  = acc.x;
    op[NW] = acc.y;
}

extern "C" void kernel_launch(void* const* d_in, const int* in_sizes, int n_in,
                              void* d_out, int out_size, void* d_ws, size_t ws_size,
                              hipStream_t stream) {
    const float* x    = (const float*)d_in[0];   // [8,32,64,64]
    const float* wt   = (const float*)d_in[1];   // [8,1024,1,3,3]
    const float* bias = (const float*)d_in[2];   // [8,1024]
    float* out = (float*)d_out;                  // [8,32,64,64]
    float* wq  = (float*)d_ws;                   // 8192*10 floats = 320 KiB

    prep_wq<<<(NC * NO * NB + 255) / 256, 256, 0, stream>>>(wt, bias, wq);

    dim3 grid(8, NO, NBATCH);                    // (hb, o, b): id % 8 == hb (XCD key)
    demolition_conv<<<grid, 256, 0, stream>>>(x, wq, out);
}